// Round 9
// baseline (793.794 us; speedup 1.0000x reference)
//
#include <hip/hip_runtime.h>
#include <hip/hip_bf16.h>

// N=8192, D=512.  Q = emb@Wqk^T+bqk (K==Q); out = softmax(QK^T/sqrt(512)) @ V.
// Softmax rows sum to 1 => out = (softmax(S)@emb) @ Wv^T + bv (V never built).
// Device dtype runtime-detected (fp32 observed). Internal: bf16 MFMA, fp32 acc.
// R8 post-mortem: wall = unique bytes from beyond L1 (~12 B/cy/CU). R9: Tq=128
// (traffic 2 GB -> 1.05 GB): 512-thr blocks (VGPR cap 256 holds accO=128),
// 64 qtiles x 4 key-splits, XOR-swizzled Qlds (128 KB, no pad) + 16 KB Plds
// (one 64-key half per phase; vb loaded exactly once). Atomic merge into
// fp32 d_out as in R8. Zero-kernel folded into transpose.

#define NTOK 8192
#define DIM  512
#define NW   16           // waves per fallback attn block

typedef unsigned short ushort_t;
typedef __attribute__((ext_vector_type(8))) __bf16 bf16x8;
typedef __attribute__((ext_vector_type(4))) float f32x4;

__device__ __forceinline__ float bf2f(ushort_t u) {
    union { unsigned int i; float f; } v; v.i = ((unsigned int)u) << 16; return v.f;
}
__device__ __forceinline__ ushort_t f2bf(float f) {
    union { float f; unsigned int i; } v; v.f = f;
    unsigned int b = v.i;
    return (ushort_t)((b + 0x7FFFu + ((b >> 16) & 1u)) >> 16);   // RNE
}
__device__ __forceinline__ __bf16 f2bfh(float f) {
    union { ushort_t u; __bf16 h; } c; c.u = f2bf(f); return c.h;
}
__device__ __forceinline__ f32x4 mfma16(bf16x8 a, bf16x8 b, f32x4 c) {
    return __builtin_amdgcn_mfma_f32_16x16x32_bf16(a, b, c, 0, 0, 0);
}
__device__ __forceinline__ bf16x8 load8(const void* p, size_t idx, bool f32) {
    if (f32) {
        const float* f = (const float*)p + idx;
        bf16x8 r;
        #pragma unroll
        for (int j = 0; j < 8; ++j) r[j] = f2bfh(f[j]);
        return r;
    }
    return *(const bf16x8*)((const ushort_t*)p + idx);
}
__device__ __forceinline__ float loadS(const void* p, size_t idx, bool f32) {
    return f32 ? ((const float*)p)[idx] : bf2f(((const ushort_t*)p)[idx]);
}

#define LDA 520   // padded stride for 32-row kernels (260 dw, %32=4: ok for b128)
#define LDP 264

// ---------------------------------------------------------------------------
// Dtype probe: flag=1 => bf16 data, flag=0 => fp32.
// ---------------------------------------------------------------------------
__global__ void detect_kernel(const ushort_t* __restrict__ emb, int* __restrict__ flag)
{
    int lane = threadIdx.x;
    int cnt = 0;
    #pragma unroll
    for (int i = 0; i < 8; ++i) {
        ushort_t u = emb[(size_t)(lane * 8 + i) * 2];
        int a = u & 0x7FFF;
        int e = (u >> 7) & 0xFF;
        if (a == 0 || (e >= 111 && e <= 143)) cnt++;
    }
    cnt += __shfl_xor(cnt, 1);  cnt += __shfl_xor(cnt, 2);  cnt += __shfl_xor(cnt, 4);
    cnt += __shfl_xor(cnt, 8);  cnt += __shfl_xor(cnt, 16); cnt += __shfl_xor(cnt, 32);
    if (lane == 0) *flag = (cnt >= 460) ? 1 : 0;
}

// ---------------------------------------------------------------------------
// embT[512][8192] (bf16) = emb^T.  Also zeroes Oacc + lsumG when provided.
// Grid (128, 8) x 256 thr.
// ---------------------------------------------------------------------------
__global__ __launch_bounds__(256)
void transpose_kernel(const int* __restrict__ flag, const void* __restrict__ emb,
                      ushort_t* __restrict__ embT,
                      float4* __restrict__ oz, float4* __restrict__ lz)
{
    __shared__ float tile[64][65];
    const bool f32 = (*flag == 0);
    const int t  = threadIdx.x;
    const int j0 = blockIdx.x * 64;
    const int d0 = blockIdx.y * 64;

    if (oz) {   // fold the accumulator zeroing into this pass
        size_t flat = ((size_t)blockIdx.y * gridDim.x + blockIdx.x) * 256 + t;
        const float4 z = {0.f, 0.f, 0.f, 0.f};
        #pragma unroll
        for (int i = 0; i < 4; ++i) oz[flat * 4 + i] = z;   // 262144*16 = 4M floats
        if (flat < 2048) lz[flat] = z;                      // 8192 floats
    }

    {
        int r = t >> 2, cs = (t & 3) * 16;
        if (f32) {
            const float* src = (const float*)emb + (size_t)(j0 + r) * DIM + d0 + cs;
            #pragma unroll
            for (int i = 0; i < 16; i += 4) {
                float4 v = *(const float4*)(src + i);
                tile[r][cs + i]     = v.x;
                tile[r][cs + i + 1] = v.y;
                tile[r][cs + i + 2] = v.z;
                tile[r][cs + i + 3] = v.w;
            }
        } else {
            const ushort_t* src = (const ushort_t*)emb + (size_t)(j0 + r) * DIM + d0 + cs;
            #pragma unroll
            for (int i = 0; i < 16; ++i) tile[r][cs + i] = bf2f(src[i]);
        }
    }
    __syncthreads();
    {
        int d = t >> 2, js = (t & 3) * 16;
        ushort_t buf[16];
        #pragma unroll
        for (int i = 0; i < 16; ++i) buf[i] = f2bf(tile[js + i][d]);
        ushort_t* dst = embT + (size_t)(d0 + d) * NTOK + j0 + js;
        *(uint4*)dst       = *(uint4*)&buf[0];
        *(uint4*)(dst + 8) = *(uint4*)&buf[8];
    }
}

// ---------------------------------------------------------------------------
// Q[8192][512](bf16, ws) = emb @ Wqk^T + bqk.  512 thr, 8 waves.
// ---------------------------------------------------------------------------
__global__ __launch_bounds__(512)
void projq_kernel(const int* __restrict__ flag, const void* __restrict__ emb,
                  const void* __restrict__ W, const void* __restrict__ bias,
                  ushort_t* __restrict__ C)
{
    __shared__ ushort_t Alds[32][LDA];
    const bool f32 = (*flag == 0);
    const int tid  = threadIdx.x;
    const int wave = tid >> 6;
    const int lane = tid & 63;
    const int quad = lane >> 4;
    const int col  = lane & 15;
    const int mblk = blockIdx.x * 32;

    #pragma unroll
    for (int i = 0; i < 4; ++i) {
        int chunk = i * 512 + tid;
        int row = chunk >> 6;
        int k8  = (chunk & 63) * 8;
        *(bf16x8*)&Alds[row][k8] = load8(emb, (size_t)(mblk + row) * 512 + k8, f32);
    }
    __syncthreads();

    f32x4 acc[2][4];
    #pragma unroll
    for (int r = 0; r < 2; ++r)
        #pragma unroll
        for (int c = 0; c < 4; ++c) acc[r][c] = (f32x4){0.f, 0.f, 0.f, 0.f};

    const int wcol = wave * 64;
    #pragma unroll
    for (int kk = 0; kk < 16; ++kk) {
        bf16x8 a0 = *(const bf16x8*)&Alds[col][kk * 32 + quad * 8];
        bf16x8 a1 = *(const bf16x8*)&Alds[16 + col][kk * 32 + quad * 8];
        #pragma unroll
        for (int c = 0; c < 4; ++c) {
            bf16x8 b = load8(W, (size_t)(wcol + c * 16 + col) * 512 + kk * 32 + quad * 8, f32);
            acc[0][c] = mfma16(a0, b, acc[0][c]);
            acc[1][c] = mfma16(a1, b, acc[1][c]);
        }
    }

    #pragma unroll
    for (int r = 0; r < 2; ++r)
        #pragma unroll
        for (int c = 0; c < 4; ++c)
            #pragma unroll
            for (int g = 0; g < 4; ++g) {
                int m = mblk + r * 16 + quad * 4 + g;
                int n = wcol + c * 16 + col;
                C[(size_t)m * DIM + n] = f2bf(acc[r][c][g] + loadS(bias, n, f32));
            }
}

// ---------------------------------------------------------------------------
// Attention partials, Tq=128: grid 256 = 64 q-tiles x 4 key-splits (2048 keys),
// 512 thr = 8 waves, KT=128/iter (16 iters). Wave w: computes S for keys
// [16w,16w+16) x all 128 rows (accS[8]); owns D cols [64w,64w+64) in PV
// (accO[8][4] = 128 VGPR; launch_bounds(512,2) caps at 256).
// Qlds XOR-swizzled (no pad, 128 KB); Plds 16 KB holds one 64-key half,
// PV in 2 key-phases so each vb is loaded exactly once. 4 barriers/iter.
// Unnormalized O and row-sums merged via device atomics (as R8).
// ---------------------------------------------------------------------------
__global__ __launch_bounds__(512, 2)
void attn_partial_kernel(const ushort_t* __restrict__ Q,
                         const ushort_t* __restrict__ embT,
                         float* __restrict__ Oacc, float* __restrict__ lsumG)
{
    __shared__ ushort_t Qlds[128 * 512];   // 131,072 B, swizzled: chunk^(row&7)
    __shared__ ushort_t Plds[128 * 64];    //  16,384 B, swizzled

    const int tid  = threadIdx.x;
    const int wave = tid >> 6;
    const int lane = tid & 63;
    const int quad = lane >> 4;
    const int col  = lane & 15;
    const int qt   = blockIdx.x >> 2;
    const int ks   = blockIdx.x & 3;
    const int q0   = qt * 128;
    const int kb0  = ks * 2048;

    {   // stage Q tile 128x512 bf16, swizzled: thread t -> row t>>2, 16 chunks
        const int srow = tid >> 2, scb = (tid & 3) * 16;
        const ushort_t* src = &Q[(size_t)(q0 + srow) * 512];
        ushort_t* dstrow = &Qlds[srow * 512];
        const int sw = (srow & 7) * 8;
        #pragma unroll
        for (int i = 0; i < 16; ++i) {
            int c8 = (scb + i) * 8;
            *(bf16x8*)&dstrow[c8 ^ sw] = *(const bf16x8*)&src[c8];
        }
    }
    __syncthreads();

    f32x4 accO[8][4];
    #pragma unroll
    for (int r = 0; r < 8; ++r)
        #pragma unroll
        for (int c = 0; c < 4; ++c) accO[r][c] = (f32x4){0.f, 0.f, 0.f, 0.f};

    float lsum[8][4];
    #pragma unroll
    for (int r = 0; r < 8; ++r)
        #pragma unroll
        for (int g = 0; g < 4; ++g) lsum[r][g] = 0.f;

    const float sc = 0.04419417382415922f * 1.4426950408889634f;  // 1/sqrt(512)*log2e
    const int colsw = (col & 7) * 8;     // read-side swizzle (row&7 == col&7 for 16-multiple bases)
    const int wd = wave * 64;

    for (int it = 0; it < 16; ++it) {
        const int j0 = kb0 + it * 128;

        // ---- S = Q_tile(128) @ K(16 keys of this wave)^T ----
        f32x4 accS[8];
        #pragma unroll
        for (int r = 0; r < 8; ++r) accS[r] = (f32x4){0.f, 0.f, 0.f, 0.f};
        const size_t keyrow = (size_t)(j0 + wave * 16 + col) * 512;
        #pragma unroll
        for (int kc4 = 0; kc4 < 4; ++kc4) {
            bf16x8 kb[4];
            #pragma unroll
            for (int k = 0; k < 4; ++k)
                kb[k] = *(const bf16x8*)&Q[keyrow + (kc4 * 4 + k) * 32 + quad * 8];
            #pragma unroll
            for (int k = 0; k < 4; ++k) {
                const int cofs = (kc4 * 4 + k) * 32 + quad * 8;
                #pragma unroll
                for (int r = 0; r < 8; ++r) {
                    bf16x8 a = *(const bf16x8*)&Qlds[(r * 16 + col) * 512 + (cofs ^ colsw)];
                    accS[r] = mfma16(a, kb[k], accS[r]);
                }
            }
        }

        // ---- P = exp2(S*sc) in-register; accumulate row sums ----
        #pragma unroll
        for (int r = 0; r < 8; ++r)
            #pragma unroll
            for (int g = 0; g < 4; ++g) {
                float v = exp2f(fminf(accS[r][g] * sc, 126.0f));
                accS[r][g] = v;
                lsum[r][g] += v;
            }

        // ---- two key-phases: waves 0-3 own phase-0 keys, 4-7 phase-1 ----
        #pragma unroll
        for (int ph = 0; ph < 2; ++ph) {
            if ((wave >> 2) == ph) {
                const int kc = (wave & 3) * 2 + (col >> 3);
                const int kpos = col & 7;
                #pragma unroll
                for (int r = 0; r < 8; ++r)
                    #pragma unroll
                    for (int g = 0; g < 4; ++g) {
                        int row = r * 16 + quad * 4 + g;
                        Plds[row * 64 + (((kc ^ (row & 7)) << 3) | kpos)] = f2bf(accS[r][g]);
                    }
            }
            __syncthreads();   // P(phase) visible; also protects prior-phase reads

            #pragma unroll
            for (int kf = 0; kf < 2; ++kf) {
                bf16x8 vb[4];
                const size_t kgl = (size_t)j0 + (ph * 2 + kf) * 32 + quad * 8;
                #pragma unroll
                for (int c = 0; c < 4; ++c)
                    vb[c] = *(const bf16x8*)&embT[(size_t)(wd + c * 16 + col) * NTOK + kgl];
                #pragma unroll
                for (int r = 0; r < 8; ++r) {
                    bf16x8 a = *(const bf16x8*)&Plds[(r * 16 + col) * 64
                                  + (((kf * 4 + quad) ^ (col & 7)) << 3)];
                    #pragma unroll
                    for (int c = 0; c < 4; ++c)
                        accO[r][c] = mfma16(a, vb[c], accO[r][c]);
                }
            }
            __syncthreads();   // PV reads done before next phase overwrites Plds
        }
    }

    // ---- merge row sums (reduce over this wave's 16 key-lanes) ----
    #pragma unroll
    for (int r = 0; r < 8; ++r)
        #pragma unroll
        for (int g = 0; g < 4; ++g) {
            float s = lsum[r][g];
            s += __shfl_xor(s, 1);
            s += __shfl_xor(s, 2);
            s += __shfl_xor(s, 4);
            s += __shfl_xor(s, 8);
            if (col == 0)
                atomicAdd(&lsumG[q0 + r * 16 + quad * 4 + g], s);
        }

    // ---- merge unnormalized O partial ----
    #pragma unroll
    for (int r = 0; r < 8; ++r)
        #pragma unroll
        for (int c = 0; c < 4; ++c)
            #pragma unroll
            for (int g = 0; g < 4; ++g)
                atomicAdd(&Oacc[(size_t)(q0 + r * 16 + quad * 4 + g) * DIM + wd + c * 16 + col],
                          accO[r][c][g]);
}

// ---------------------------------------------------------------------------
// Final: out = (Oacc / l) @ Wv^T + bv, in place on d_out (row-local).
// ---------------------------------------------------------------------------
__global__ __launch_bounds__(512)
void normproj_kernel(const int* __restrict__ flag, const float* __restrict__ lsumG,
                     const void* __restrict__ Wv, const void* __restrict__ bv,
                     void* __restrict__ Out)
{
    __shared__ ushort_t Alds[32][LDA];
    const bool f32 = (*flag == 0);
    const int tid  = threadIdx.x;
    const int wave = tid >> 6;
    const int lane = tid & 63;
    const int quad = lane >> 4;
    const int col  = lane & 15;
    const int mblk = blockIdx.x * 32;
    const float* Oacc = (const float*)Out;

    #pragma unroll
    for (int i = 0; i < 4; ++i) {
        int chunk = i * 512 + tid;
        int row = chunk >> 6;
        int k8  = (chunk & 63) * 8;
        float rv = 1.0f / lsumG[mblk + row];
        const float* src = Oacc + (size_t)(mblk + row) * 512 + k8;
        bf16x8 t;
        #pragma unroll
        for (int j = 0; j < 8; ++j) t[j] = f2bfh(src[j] * rv);
        *(bf16x8*)&Alds[row][k8] = t;
    }
    __syncthreads();

    f32x4 acc[2][4];
    #pragma unroll
    for (int r = 0; r < 2; ++r)
        #pragma unroll
        for (int c = 0; c < 4; ++c) acc[r][c] = (f32x4){0.f, 0.f, 0.f, 0.f};

    const int wcol = wave * 64;
    #pragma unroll
    for (int kk = 0; kk < 16; ++kk) {
        bf16x8 a0 = *(const bf16x8*)&Alds[col][kk * 32 + quad * 8];
        bf16x8 a1 = *(const bf16x8*)&Alds[16 + col][kk * 32 + quad * 8];
        #pragma unroll
        for (int c = 0; c < 4; ++c) {
            bf16x8 b = load8(Wv, (size_t)(wcol + c * 16 + col) * 512 + kk * 32 + quad * 8, f32);
            acc[0][c] = mfma16(a0, b, acc[0][c]);
            acc[1][c] = mfma16(a1, b, acc[1][c]);
        }
    }
    __syncthreads();

    #pragma unroll
    for (int r = 0; r < 2; ++r)
        #pragma unroll
        for (int c = 0; c < 4; ++c)
            #pragma unroll
            for (int g = 0; g < 4; ++g) {
                int m = mblk + r * 16 + quad * 4 + g;
                int n = wcol + c * 16 + col;
                float v = acc[r][c][g] + loadS(bv, n, f32);
                if (f32) ((float*)Out)[(size_t)m * DIM + n] = v;
                else     ((ushort_t*)Out)[(size_t)m * DIM + n] = f2bf(v);
            }
}

// ---------------------------------------------------------------------------
// Fallback fused attention (R6 structure) for smaller workspaces.
// ---------------------------------------------------------------------------
template <int VT>
__global__ __launch_bounds__(1024)
void attn_kernel(const int* __restrict__ flag, const ushort_t* __restrict__ Q,
                 const void* __restrict__ embOrT, const void* __restrict__ Wv,
                 const void* __restrict__ bv, void* __restrict__ Out)
{
    __shared__ ushort_t Qlds[32][LDA];
    __shared__ ushort_t Plds[2][32][LDP];
    __shared__ float    Lpart[NW][32];

    const bool f32 = (*flag == 0);
    const int tid  = threadIdx.x;
    const int wave = tid >> 6;
    const int lane = tid & 63;
    const int quad = lane >> 4;
    const int col  = lane & 15;
    const int q0   = blockIdx.x * 32;

    #pragma unroll
    for (int i = 0; i < 2; ++i) {
        int chunk = i * 1024 + tid;
        int row = chunk >> 6;
        int k8  = (chunk & 63) * 8;
        *(bf16x8*)&Qlds[row][k8] = *(const bf16x8*)&Q[(size_t)(q0 + row) * 512 + k8];
    }
    __syncthreads();

    f32x4 accO[2][2];
    #pragma unroll
    for (int r = 0; r < 2; ++r)
        #pragma unroll
        for (int c = 0; c < 2; ++c) accO[r][c] = (f32x4){0.f, 0.f, 0.f, 0.f};

    float lsum[2][4];
    #pragma unroll
    for (int r = 0; r < 2; ++r)
        #pragma unroll
        for (int g = 0; g < 4; ++g) lsum[r][g] = 0.f;

    const float sc = 0.04419417382415922f * 1.4426950408889634f;
    const int wOcol = wave * 32;

    for (int it = 0; it < 32; ++it) {
        const int j0  = it * 256;
        const int buf = it & 1;

        bf16x8 kb[16];
        const size_t keyrow = (size_t)(j0 + wave * 16 + col) * 512;
        #pragma unroll
        for (int kk = 0; kk < 16; ++kk)
            kb[kk] = *(const bf16x8*)&Q[keyrow + kk * 32 + quad * 8];

        f32x4 accS[2];
        accS[0] = (f32x4){0.f, 0.f, 0.f, 0.f};
        accS[1] = (f32x4){0.f, 0.f, 0.f, 0.f};
        #pragma unroll
        for (int kk = 0; kk < 16; ++kk) {
            bf16x8 a0 = *(const bf16x8*)&Qlds[col][kk * 32 + quad * 8];
            bf16x8 a1 = *(const bf16x8*)&Qlds[16 + col][kk * 32 + quad * 8];
            accS[0] = mfma16(a0, kb[kk], accS[0]);
            accS[1] = mfma16(a1, kb[kk], accS[1]);
        }

        bf16x8 vb[16];
        if (VT) {
            #pragma unroll
            for (int kk = 0; kk < 8; ++kk)
                #pragma unroll
                for (int c = 0; c < 2; ++c)
                    vb[kk * 2 + c] = *(const bf16x8*)((const ushort_t*)embOrT
                        + (size_t)(wOcol + c * 16 + col) * NTOK + j0 + kk * 32 + quad * 8);
        } else {
            #pragma unroll
            for (int kk = 0; kk < 8; ++kk)
                #pragma unroll
                for (int c = 0; c < 2; ++c) {
                    size_t base = (size_t)(j0 + kk * 32 + quad * 8) * 512 + (wOcol + c * 16 + col);
                    bf16x8 b;
                    if (f32) {
                        const float* bp = (const float*)embOrT + base;
                        #pragma unroll
                        for (int j = 0; j < 8; ++j) b[j] = f2bfh(bp[(size_t)j * 512]);
                    } else {
                        const __bf16* bp = (const __bf16*)embOrT + base;
                        #pragma unroll
                        for (int j = 0; j < 8; ++j) b[j] = bp[(size_t)j * 512];
                    }
                    vb[kk * 2 + c] = b;
                }
        }

        #pragma unroll
        for (int r = 0; r < 2; ++r)
            #pragma unroll
            for (int g = 0; g < 4; ++g) {
                float p = exp2f(fminf(accS[r][g] * sc, 126.0f));
                lsum[r][g] += p;
                Plds[buf][r * 16 + quad * 4 + g][wave * 16 + col] = f2bf(p);
            }

        __syncthreads();

        #pragma unroll
        for (int kk = 0; kk < 8; ++kk) {
            bf16x8 a0 = *(const bf16x8*)&Plds[buf][col][kk * 32 + quad * 8];
            bf16x8 a1 = *(const bf16x8*)&Plds[buf][16 + col][kk * 32 + quad * 8];
            #pragma unroll
            for (int c = 0; c < 2; ++c) {
                accO[0][c] = mfma16(a0, vb[kk * 2 + c], accO[0][c]);
                accO[1][c] = mfma16(a1, vb[kk * 2 + c], accO[1][c]);
            }
        }
    }

    #pragma unroll
    for (int r = 0; r < 2; ++r)
        #pragma unroll
        for (int g = 0; g < 4; ++g) {
            float s = lsum[r][g];
            s += __shfl_xor(s, 1);
            s += __shfl_xor(s, 2);
            s += __shfl_xor(s, 4);
            s += __shfl_xor(s, 8);
            lsum[r][g] = s;
        }
    if (col == 0) {
        #pragma unroll
        for (int r = 0; r < 2; ++r)
            #pragma unroll
            for (int g = 0; g < 4; ++g)
                Lpart[wave][r * 16 + quad * 4 + g] = lsum[r][g];
    }
    __syncthreads();

    #pragma unroll
    for (int r = 0; r < 2; ++r) {
        float rinv[4];
        #pragma unroll
        for (int g = 0; g < 4; ++g) {
            float t = 0.f;
            #pragma unroll
            for (int w = 0; w < NW; ++w) t += Lpart[w][r * 16 + quad * 4 + g];
            rinv[g] = 1.0f / t;
        }
        #pragma unroll
        for (int c = 0; c < 2; ++c)
            #pragma unroll
            for (int g = 0; g < 4; ++g)
                Qlds[r * 16 + quad * 4 + g][wOcol + c * 16 + col] = f2bf(accO[r][c][g] * rinv[g]);
    }
    __syncthreads();

    f32x4 acc2[2][2];
    #pragma unroll
    for (int r = 0; r < 2; ++r)
        #pragma unroll
        for (int c = 0; c < 2; ++c) acc2[r][c] = (f32x4){0.f, 0.f, 0.f, 0.f};

    #pragma unroll
    for (int kk = 0; kk < 16; ++kk) {
        bf16x8 a0 = *(const bf16x8*)&Qlds[col][kk * 32 + quad * 8];
        bf16x8 a1 = *(const bf16x8*)&Qlds[16 + col][kk * 32 + quad * 8];
        #pragma unroll
        for (int c = 0; c < 2; ++c) {
            bf16x8 b = load8(Wv, (size_t)(wOcol + c * 16 + col) * 512 + kk * 32 + quad * 8, f32);
            acc2[0][c] = mfma16(a0, b, acc2[0][c]);
            acc2[1][c] = mfma16(a1, b, acc2[1][c]);
        }
    }

    #pragma unroll
    for (int r = 0; r < 2; ++r)
        #pragma unroll
        for (int c = 0; c < 2; ++c)
            #pragma unroll
            for (int g = 0; g < 4; ++g) {
                int m = q0 + r * 16 + quad * 4 + g;
                int n = wOcol + c * 16 + col;
                float v = acc2[r][c][g] + loadS(bv, n, f32);
                if (f32) ((float*)Out)[(size_t)m * DIM + n] = v;
                else     ((ushort_t*)Out)[(size_t)m * DIM + n] = f2bf(v);
            }
}

extern "C" void kernel_launch(void* const* d_in, const int* in_sizes, int n_in,
                              void* d_out, int out_size, void* d_ws, size_t ws_size,
                              hipStream_t stream)
{
    const void* emb = d_in[0];
    const void* Wqk = d_in[1];
    const void* bqk = d_in[2];
    const void* Wv  = d_in[3];
    const void* bv  = d_in[4];

    const size_t QB = (size_t)NTOK * DIM * 2;            // 8 MB bf16

    int*      flag = (int*)d_ws;
    float*    lsumG = (float*)((char*)d_ws + 64);        // 32 KB
    ushort_t* embT = (ushort_t*)((char*)d_ws + 64 + NTOK * 4);
    ushort_t* Qws  = embT + (size_t)DIM * NTOK;

    const size_t need3 = 64 + NTOK * 4 + 2 * QB;         // atomic-merge path
    const size_t need2 = 64 + 2 * QB;                    // R6 fast path

    detect_kernel<<<dim3(1), dim3(64), 0, stream>>>((const ushort_t*)emb, flag);

    if (ws_size >= need3) {
        transpose_kernel<<<dim3(NTOK / 64, DIM / 64), dim3(256), 0, stream>>>(
            flag, emb, embT, (float4*)d_out, (float4*)lsumG);
        projq_kernel<<<dim3(NTOK / 32), dim3(512), 0, stream>>>(flag, emb, Wqk, bqk, Qws);
        attn_partial_kernel<<<dim3(256), dim3(512), 0, stream>>>(Qws, embT,
                                                                 (float*)d_out, lsumG);
        normproj_kernel<<<dim3(NTOK / 32), dim3(512), 0, stream>>>(flag, lsumG, Wv, bv, d_out);
    } else if (ws_size >= need2) {
        ushort_t* embT2 = (ushort_t*)((char*)d_ws + 64);
        ushort_t* Qws2  = embT2 + (size_t)DIM * NTOK;
        transpose_kernel<<<dim3(NTOK / 64, DIM / 64), dim3(256), 0, stream>>>(
            flag, emb, embT2, nullptr, nullptr);
        projq_kernel<<<dim3(NTOK / 32), dim3(512), 0, stream>>>(flag, emb, Wqk, bqk, Qws2);
        attn_kernel<1><<<dim3(NTOK / 32), dim3(1024), 0, stream>>>(flag, Qws2, embT2, Wv, bv, d_out);
    } else {
        ushort_t* Qsm = (ushort_t*)((char*)d_ws + 64);
        projq_kernel<<<dim3(NTOK / 32), dim3(512), 0, stream>>>(flag, emb, Wqk, bqk, Qsm);
        attn_kernel<0><<<dim3(NTOK / 32), dim3(1024), 0, stream>>>(flag, Qsm, emb, Wv, bv, d_out);
    }
}

// Round 10
// 597.215 us; speedup vs baseline: 1.3292x; 1.3292x over previous
//
#include <hip/hip_runtime.h>
#include <hip/hip_bf16.h>

// N=8192, D=512.  Q = emb@Wqk^T+bqk (K==Q); out = softmax(QK^T/sqrt(512)) @ V.
// Softmax rows sum to 1 => out = (softmax(S)@emb) @ Wv^T + bv (V never built).
// R9 post-mortem: 512-thr Tq=128 spilled (VGPR demand ~200 vs 128) -> 1.15 GB
// scratch HBM traffic; R8-vs-R6 delta shows ~110us atomic-merge tail.
// R10: no atomics for O (plain per-split partial buffers, full-coverage
// disjoint stores -> poison-proof, no zeroing); lsum merged via tiny atomics.
//  Path A (ws>=64.1MB): Tq=128 split-4, 1024thr/16 waves, fp32 partials
//    (3 in ws + 1 in d_out), VGPR budget ~120 <= 128 cap.
//  Path B (ws>=16.03MB, proven): R8's Tq=64 split-2 kernel, bf16 partials in
//    d_out halves.
// Then: reduce+normalize -> T (bf16, overwrites dead Q slot) -> projv -> out.

#define NTOK 8192
#define DIM  512

typedef unsigned short ushort_t;
typedef __attribute__((ext_vector_type(8))) __bf16 bf16x8;
typedef __attribute__((ext_vector_type(4))) float f32x4;

__device__ __forceinline__ float bf2f(ushort_t u) {
    union { unsigned int i; float f; } v; v.i = ((unsigned int)u) << 16; return v.f;
}
__device__ __forceinline__ ushort_t f2bf(float f) {
    union { float f; unsigned int i; } v; v.f = f;
    unsigned int b = v.i;
    return (ushort_t)((b + 0x7FFFu + ((b >> 16) & 1u)) >> 16);   // RNE
}
__device__ __forceinline__ __bf16 f2bfh(float f) {
    union { ushort_t u; __bf16 h; } c; c.u = f2bf(f); return c.h;
}
__device__ __forceinline__ f32x4 mfma16(bf16x8 a, bf16x8 b, f32x4 c) {
    return __builtin_amdgcn_mfma_f32_16x16x32_bf16(a, b, c, 0, 0, 0);
}
__device__ __forceinline__ bf16x8 load8(const void* p, size_t idx, bool f32) {
    if (f32) {
        const float* f = (const float*)p + idx;
        bf16x8 r;
        #pragma unroll
        for (int j = 0; j < 8; ++j) r[j] = f2bfh(f[j]);
        return r;
    }
    return *(const bf16x8*)((const ushort_t*)p + idx);
}
__device__ __forceinline__ float loadS(const void* p, size_t idx, bool f32) {
    return f32 ? ((const float*)p)[idx] : bf2f(((const ushort_t*)p)[idx]);
}

#define LDA 520   // 260 dw, %32=4: uniform 2 dw/bank for b128 row reads
#define LDP 264

// ---------------------------------------------------------------------------
// Dtype probe: flag=1 => bf16 data, flag=0 => fp32.
// ---------------------------------------------------------------------------
__global__ void detect_kernel(const ushort_t* __restrict__ emb, int* __restrict__ flag)
{
    int lane = threadIdx.x;
    int cnt = 0;
    #pragma unroll
    for (int i = 0; i < 8; ++i) {
        ushort_t u = emb[(size_t)(lane * 8 + i) * 2];
        int a = u & 0x7FFF;
        int e = (u >> 7) & 0xFF;
        if (a == 0 || (e >= 111 && e <= 143)) cnt++;
    }
    cnt += __shfl_xor(cnt, 1);  cnt += __shfl_xor(cnt, 2);  cnt += __shfl_xor(cnt, 4);
    cnt += __shfl_xor(cnt, 8);  cnt += __shfl_xor(cnt, 16); cnt += __shfl_xor(cnt, 32);
    if (lane == 0) *flag = (cnt >= 460) ? 1 : 0;
}

// ---------------------------------------------------------------------------
// embT[512][8192] (bf16) = emb^T.  Also zeroes lsumG (32 KB) when provided.
// ---------------------------------------------------------------------------
__global__ __launch_bounds__(256)
void transpose_kernel(const int* __restrict__ flag, const void* __restrict__ emb,
                      ushort_t* __restrict__ embT, float4* __restrict__ lz)
{
    __shared__ float tile[64][65];
    const bool f32 = (*flag == 0);
    const int t  = threadIdx.x;
    const int j0 = blockIdx.x * 64;
    const int d0 = blockIdx.y * 64;

    if (lz) {
        size_t flat = ((size_t)blockIdx.y * gridDim.x + blockIdx.x) * 256 + t;
        if (flat < 2048) lz[flat] = (float4){0.f, 0.f, 0.f, 0.f};   // 8192 floats
    }

    {
        int r = t >> 2, cs = (t & 3) * 16;
        if (f32) {
            const float* src = (const float*)emb + (size_t)(j0 + r) * DIM + d0 + cs;
            #pragma unroll
            for (int i = 0; i < 16; i += 4) {
                float4 v = *(const float4*)(src + i);
                tile[r][cs + i]     = v.x;
                tile[r][cs + i + 1] = v.y;
                tile[r][cs + i + 2] = v.z;
                tile[r][cs + i + 3] = v.w;
            }
        } else {
            const ushort_t* src = (const ushort_t*)emb + (size_t)(j0 + r) * DIM + d0 + cs;
            #pragma unroll
            for (int i = 0; i < 16; ++i) tile[r][cs + i] = bf2f(src[i]);
        }
    }
    __syncthreads();
    {
        int d = t >> 2, js = (t & 3) * 16;
        ushort_t buf[16];
        #pragma unroll
        for (int i = 0; i < 16; ++i) buf[i] = f2bf(tile[js + i][d]);
        ushort_t* dst = embT + (size_t)(d0 + d) * NTOK + j0 + js;
        *(uint4*)dst       = *(uint4*)&buf[0];
        *(uint4*)(dst + 8) = *(uint4*)&buf[8];
    }
}

// ---------------------------------------------------------------------------
// Q[8192][512](bf16, ws) = emb @ Wqk^T + bqk.  512 thr, 8 waves.
// ---------------------------------------------------------------------------
__global__ __launch_bounds__(512)
void projq_kernel(const int* __restrict__ flag, const void* __restrict__ emb,
                  const void* __restrict__ W, const void* __restrict__ bias,
                  ushort_t* __restrict__ C)
{
    __shared__ ushort_t Alds[32][LDA];
    const bool f32 = (*flag == 0);
    const int tid  = threadIdx.x;
    const int wave = tid >> 6;
    const int lane = tid & 63;
    const int quad = lane >> 4;
    const int col  = lane & 15;
    const int mblk = blockIdx.x * 32;

    #pragma unroll
    for (int i = 0; i < 4; ++i) {
        int chunk = i * 512 + tid;
        int row = chunk >> 6;
        int k8  = (chunk & 63) * 8;
        *(bf16x8*)&Alds[row][k8] = load8(emb, (size_t)(mblk + row) * 512 + k8, f32);
    }
    __syncthreads();

    f32x4 acc[2][4];
    #pragma unroll
    for (int r = 0; r < 2; ++r)
        #pragma unroll
        for (int c = 0; c < 4; ++c) acc[r][c] = (f32x4){0.f, 0.f, 0.f, 0.f};

    const int wcol = wave * 64;
    #pragma unroll
    for (int kk = 0; kk < 16; ++kk) {
        bf16x8 a0 = *(const bf16x8*)&Alds[col][kk * 32 + quad * 8];
        bf16x8 a1 = *(const bf16x8*)&Alds[16 + col][kk * 32 + quad * 8];
        #pragma unroll
        for (int c = 0; c < 4; ++c) {
            bf16x8 b = load8(W, (size_t)(wcol + c * 16 + col) * 512 + kk * 32 + quad * 8, f32);
            acc[0][c] = mfma16(a0, b, acc[0][c]);
            acc[1][c] = mfma16(a1, b, acc[1][c]);
        }
    }

    #pragma unroll
    for (int r = 0; r < 2; ++r)
        #pragma unroll
        for (int c = 0; c < 4; ++c)
            #pragma unroll
            for (int g = 0; g < 4; ++g) {
                int m = mblk + r * 16 + quad * 4 + g;
                int n = wcol + c * 16 + col;
                C[(size_t)m * DIM + n] = f2bf(acc[r][c][g] + loadS(bias, n, f32));
            }
}

// ---------------------------------------------------------------------------
// Path A attention: Tq=128, split-4. Grid 256 = 64 q-tiles x 4 key-splits
// (2048 keys each), 1024 thr = 16 waves, KT=128/iter (16 iters), two-phase
// Plds (16 KB). Wave w: kg=w&7 (16 keys), rg=w>>3 (64 S-rows); owns 32 D-cols.
// Plain fp32 partial stores (disjoint, full coverage). lsum via tiny atomics.
// VGPR budget: accO 64 + accS 16 + lsum 16 + transients ~24 <= 128 cap.
// ---------------------------------------------------------------------------
__global__ __launch_bounds__(1024)
void attn128_kernel(const ushort_t* __restrict__ Q, const ushort_t* __restrict__ embT,
                    float* __restrict__ p0, float* __restrict__ p1,
                    float* __restrict__ p2, float* __restrict__ p3,
                    float* __restrict__ lsumG)
{
    __shared__ ushort_t Qlds[128 * 512];   // 128 KB, swizzled chunk^(row&7)
    __shared__ ushort_t Plds[128 * 64];    //  16 KB, one 64-key phase

    const int tid  = threadIdx.x;
    const int wave = tid >> 6;
    const int lane = tid & 63;
    const int quad = lane >> 4;
    const int col  = lane & 15;
    const int qt   = blockIdx.x >> 2;
    const int ks   = blockIdx.x & 3;
    const int q0   = qt * 128;
    const int kb0  = ks * 2048;
    float* Ps = (ks == 0) ? p0 : (ks == 1) ? p1 : (ks == 2) ? p2 : p3;

    {   // stage Q tile 128x512 bf16 swizzled: thread t -> row t>>3, 8 chunks
        const int row = tid >> 3;
        const ushort_t* src = &Q[(size_t)(q0 + row) * 512];
        ushort_t* dst = &Qlds[row * 512];
        const int sw = (row & 7) * 8;
        const int cb = (tid & 7) * 64;
        #pragma unroll
        for (int i = 0; i < 8; ++i) {
            int c8 = cb + i * 8;
            *(bf16x8*)&dst[c8 ^ sw] = *(const bf16x8*)&src[c8];
        }
    }
    __syncthreads();

    f32x4 accO[8][2];
    #pragma unroll
    for (int r = 0; r < 8; ++r)
        #pragma unroll
        for (int c = 0; c < 2; ++c) accO[r][c] = (f32x4){0.f, 0.f, 0.f, 0.f};

    float lsum[4][4];
    #pragma unroll
    for (int r = 0; r < 4; ++r)
        #pragma unroll
        for (int g = 0; g < 4; ++g) lsum[r][g] = 0.f;

    const float sc = 0.04419417382415922f * 1.4426950408889634f;  // 1/sqrt(512)*log2e
    const int kg = wave & 7;     // key-group (16 keys of 128)
    const int rg = wave >> 3;    // row-group (64 rows of 128)
    const int wd = wave * 32;    // owned D-col base in PV
    const int colsw = (col & 7) * 8;

    for (int it = 0; it < 16; ++it) {
        const int j0 = kb0 + it * 128;

        // ---- S(rg's 64 rows x kg's 16 keys) = Q_tile @ K^T ----
        f32x4 accS[4];
        #pragma unroll
        for (int r = 0; r < 4; ++r) accS[r] = (f32x4){0.f, 0.f, 0.f, 0.f};
        const size_t keyrow = (size_t)(j0 + kg * 16 + col) * 512;
        #pragma unroll
        for (int kc4 = 0; kc4 < 4; ++kc4) {
            bf16x8 kb4[4];
            #pragma unroll
            for (int k = 0; k < 4; ++k)
                kb4[k] = *(const bf16x8*)&Q[keyrow + (kc4 * 4 + k) * 32 + quad * 8];
            #pragma unroll
            for (int k = 0; k < 4; ++k) {
                const int cofs = (kc4 * 4 + k) * 32 + quad * 8;
                #pragma unroll
                for (int r = 0; r < 4; ++r) {
                    bf16x8 a = *(const bf16x8*)&Qlds[(rg * 64 + r * 16 + col) * 512
                                                     + (cofs ^ colsw)];
                    accS[r] = mfma16(a, kb4[k], accS[r]);
                }
            }
        }

        // ---- P = exp2(S*sc) in-register; accumulate row sums ----
        #pragma unroll
        for (int r = 0; r < 4; ++r)
            #pragma unroll
            for (int g = 0; g < 4; ++g) {
                float v = exp2f(fminf(accS[r][g] * sc, 126.0f));
                accS[r][g] = v;
                lsum[r][g] += v;
            }

        // ---- two 64-key phases: kg 0-3 -> phase 0, kg 4-7 -> phase 1 ----
        #pragma unroll
        for (int ph = 0; ph < 2; ++ph) {
            if ((kg >> 2) == ph) {
                const int klb = (kg & 3) * 16;          // key base within phase
                #pragma unroll
                for (int r = 0; r < 4; ++r)
                    #pragma unroll
                    for (int g = 0; g < 4; ++g) {
                        int prow = rg * 64 + r * 16 + quad * 4 + g;
                        int kl   = klb + col;            // 0..63
                        int kch  = kl >> 3;
                        Plds[prow * 64 + (((kch ^ (prow & 7)) << 3) | (kl & 7))]
                            = f2bf(accS[r][g]);
                    }
            }
            __syncthreads();   // P(phase) visible; also protects prior-phase reads

            #pragma unroll
            for (int kf = 0; kf < 2; ++kf) {
                const size_t kgl = (size_t)j0 + ph * 64 + kf * 32 + quad * 8;
                bf16x8 vb0 = *(const bf16x8*)&embT[(size_t)(wd + col) * NTOK + kgl];
                bf16x8 vb1 = *(const bf16x8*)&embT[(size_t)(wd + 16 + col) * NTOK + kgl];
                #pragma unroll
                for (int r = 0; r < 8; ++r) {
                    int prow = r * 16 + col;
                    bf16x8 a = *(const bf16x8*)&Plds[prow * 64
                                  + (((kf * 4 + quad) ^ (prow & 7)) << 3)];
                    accO[r][0] = mfma16(a, vb0, accO[r][0]);
                    accO[r][1] = mfma16(a, vb1, accO[r][1]);
                }
            }
            __syncthreads();   // PV reads done before next phase overwrites Plds
        }
    }

    // ---- merge row sums (reduce over this wave's 16 key-lanes) ----
    #pragma unroll
    for (int r = 0; r < 4; ++r)
        #pragma unroll
        for (int g = 0; g < 4; ++g) {
            float s = lsum[r][g];
            s += __shfl_xor(s, 1);
            s += __shfl_xor(s, 2);
            s += __shfl_xor(s, 4);
            s += __shfl_xor(s, 8);
            if (col == 0)
                atomicAdd(&lsumG[q0 + rg * 64 + r * 16 + quad * 4 + g], s);
        }

    // ---- plain fp32 partial store: full 128 rows x 512 cols, disjoint ----
    #pragma unroll
    for (int r = 0; r < 8; ++r)
        #pragma unroll
        for (int c = 0; c < 2; ++c)
            #pragma unroll
            for (int g = 0; g < 4; ++g)
                Ps[(size_t)(q0 + r * 16 + quad * 4 + g) * DIM + wd + c * 16 + col]
                    = accO[r][c][g];
}

// ---------------------------------------------------------------------------
// Path B attention: R8's proven Tq=64 split-2 kernel; bf16 partial stores
// into d_out halves instead of atomics.  1024 thr, KT=256, 16 iters.
// ---------------------------------------------------------------------------
__global__ __launch_bounds__(1024)
void attn64_kernel(const ushort_t* __restrict__ Q, const ushort_t* __restrict__ embT,
                   ushort_t* __restrict__ Opart, float* __restrict__ lsumG)
{
    __shared__ ushort_t Qlds[64][LDA];
    __shared__ ushort_t Plds[64][LDP];

    const int tid  = threadIdx.x;
    const int wave = tid >> 6;
    const int lane = tid & 63;
    const int quad = lane >> 4;
    const int col  = lane & 15;
    const int qt   = blockIdx.x & 127;
    const int ks   = blockIdx.x >> 7;
    const int q0   = qt * 64;
    const int kbase = ks * 4096;

    #pragma unroll
    for (int i = 0; i < 4; ++i) {
        int chunk = i * 1024 + tid;
        int row = chunk >> 6;
        int k8  = (chunk & 63) * 8;
        *(bf16x8*)&Qlds[row][k8] = *(const bf16x8*)&Q[(size_t)(q0 + row) * 512 + k8];
    }
    __syncthreads();

    f32x4 accO[4][2];
    #pragma unroll
    for (int r = 0; r < 4; ++r)
        #pragma unroll
        for (int c = 0; c < 2; ++c) accO[r][c] = (f32x4){0.f, 0.f, 0.f, 0.f};

    float lsum[4][4];
    #pragma unroll
    for (int r = 0; r < 4; ++r)
        #pragma unroll
        for (int g = 0; g < 4; ++g) lsum[r][g] = 0.f;

    const float sc = 0.04419417382415922f * 1.4426950408889634f;
    const int wd = wave * 32;

    for (int it = 0; it < 16; ++it) {
        const int j0 = kbase + it * 256;

        bf16x8 kb[16];
        const size_t keyrow = (size_t)(j0 + wave * 16 + col) * 512;
        #pragma unroll
        for (int kk = 0; kk < 16; ++kk)
            kb[kk] = *(const bf16x8*)&Q[keyrow + kk * 32 + quad * 8];

        f32x4 accS[4];
        #pragma unroll
        for (int r = 0; r < 4; ++r) accS[r] = (f32x4){0.f, 0.f, 0.f, 0.f};
        #pragma unroll
        for (int kk = 0; kk < 16; ++kk) {
            #pragma unroll
            for (int r = 0; r < 4; ++r) {
                bf16x8 a = *(const bf16x8*)&Qlds[r * 16 + col][kk * 32 + quad * 8];
                accS[r] = mfma16(a, kb[kk], accS[r]);
            }
        }

        bf16x8 vb[16];
        #pragma unroll
        for (int kk = 0; kk < 8; ++kk)
            #pragma unroll
            for (int c = 0; c < 2; ++c)
                vb[kk * 2 + c] = *(const bf16x8*)&embT[
                    (size_t)(wd + c * 16 + col) * NTOK + j0 + kk * 32 + quad * 8];

        __syncthreads();

        #pragma unroll
        for (int r = 0; r < 4; ++r)
            #pragma unroll
            for (int g = 0; g < 4; ++g) {
                float p = exp2f(fminf(accS[r][g] * sc, 126.0f));
                lsum[r][g] += p;
                Plds[r * 16 + quad * 4 + g][wave * 16 + col] = f2bf(p);
            }

        __syncthreads();

        #pragma unroll
        for (int kk = 0; kk < 8; ++kk) {
            #pragma unroll
            for (int r = 0; r < 4; ++r) {
                bf16x8 a = *(const bf16x8*)&Plds[r * 16 + col][kk * 32 + quad * 8];
                #pragma unroll
                for (int c = 0; c < 2; ++c)
                    accO[r][c] = mfma16(a, vb[kk * 2 + c], accO[r][c]);
            }
        }
    }

    #pragma unroll
    for (int r = 0; r < 4; ++r)
        #pragma unroll
        for (int g = 0; g < 4; ++g) {
            float s = lsum[r][g];
            s += __shfl_xor(s, 1);
            s += __shfl_xor(s, 2);
            s += __shfl_xor(s, 4);
            s += __shfl_xor(s, 8);
            if (col == 0)
                atomicAdd(&lsumG[q0 + r * 16 + quad * 4 + g], s);
        }

    ushort_t* Ps = Opart + (size_t)ks * NTOK * DIM;
    #pragma unroll
    for (int r = 0; r < 4; ++r)
        #pragma unroll
        for (int c = 0; c < 2; ++c)
            #pragma unroll
            for (int g = 0; g < 4; ++g)
                Ps[(size_t)(q0 + r * 16 + quad * 4 + g) * DIM + wd + c * 16 + col]
                    = f2bf(accO[r][c][g]);
}

// ---------------------------------------------------------------------------
// T[m][n](bf16) = (sum_s Ps[m][n]) / lsumG[m].  2048 blocks x 256 thr.
// ---------------------------------------------------------------------------
__global__ __launch_bounds__(256)
void reduce_kernel(int ns, int pf32,
                   const void* __restrict__ p0, const void* __restrict__ p1,
                   const void* __restrict__ p2, const void* __restrict__ p3,
                   const float* __restrict__ lsumG, ushort_t* __restrict__ T)
{
    size_t gid = (size_t)blockIdx.x * 256 + threadIdx.x;
    size_t e8  = gid * 8;
    int m = (int)(gid >> 6);                 // e8 / 512
    float rv = 1.0f / lsumG[m];

    float s[8];
    #pragma unroll
    for (int j = 0; j < 8; ++j) s[j] = 0.f;

    const void* ps[4] = {p0, p1, p2, p3};
    for (int t = 0; t < ns; ++t) {
        if (pf32) {
            const float* f = (const float*)ps[t] + e8;
            float4 a = *(const float4*)f;
            float4 b = *(const float4*)(f + 4);
            s[0] += a.x; s[1] += a.y; s[2] += a.z; s[3] += a.w;
            s[4] += b.x; s[5] += b.y; s[6] += b.z; s[7] += b.w;
        } else {
            bf16x8 v = *(const bf16x8*)((const ushort_t*)ps[t] + e8);
            #pragma unroll
            for (int j = 0; j < 8; ++j) s[j] += (float)v[j];
        }
    }
    bf16x8 o;
    #pragma unroll
    for (int j = 0; j < 8; ++j) o[j] = f2bfh(s[j] * rv);
    *(bf16x8*)&T[e8] = o;
}

// ---------------------------------------------------------------------------
// out = T @ Wv^T + bv.  T bf16 (ws), out dtype per flag.  256 blk x 512 thr.
// ---------------------------------------------------------------------------
__global__ __launch_bounds__(512)
void projv_kernel(const int* __restrict__ flag, const ushort_t* __restrict__ T,
                  const void* __restrict__ W, const void* __restrict__ bias,
                  void* __restrict__ Out)
{
    __shared__ ushort_t Alds[32][LDA];
    const bool f32 = (*flag == 0);
    const int tid  = threadIdx.x;
    const int wave = tid >> 6;
    const int lane = tid & 63;
    const int quad = lane >> 4;
    const int col  = lane & 15;
    const int mblk = blockIdx.x * 32;

    #pragma unroll
    for (int i = 0; i < 4; ++i) {
        int chunk = i * 512 + tid;
        int row = chunk >> 6;
        int k8  = (chunk & 63) * 8;
        *(bf16x8*)&Alds[row][k8] = *(const bf16x8*)&T[(size_t)(mblk + row) * 512 + k8];
    }
    __syncthreads();

    f32x4 acc[2][4];
    #pragma unroll
    for (int r = 0; r < 2; ++r)
        #pragma unroll
        for (int c = 0; c < 4; ++c) acc[r][c] = (f32x4){0.f, 0.f, 0.f, 0.f};

    const int wcol = wave * 64;
    #pragma unroll
    for (int kk = 0; kk < 16; ++kk) {
        bf16x8 a0 = *(const bf16x8*)&Alds[col][kk * 32 + quad * 8];
        bf16x8 a1 = *(const bf16x8*)&Alds[16 + col][kk * 32 + quad * 8];
        #pragma unroll
        for (int c = 0; c < 4; ++c) {
            bf16x8 b = load8(W, (size_t)(wcol + c * 16 + col) * 512 + kk * 32 + quad * 8, f32);
            acc[0][c] = mfma16(a0, b, acc[0][c]);
            acc[1][c] = mfma16(a1, b, acc[1][c]);
        }
    }

    #pragma unroll
    for (int r = 0; r < 2; ++r)
        #pragma unroll
        for (int c = 0; c < 4; ++c)
            #pragma unroll
            for (int g = 0; g < 4; ++g) {
                int m = mblk + r * 16 + quad * 4 + g;
                int n = wcol + c * 16 + col;
                float v = acc[r][c][g] + loadS(bias, n, f32);
                if (f32) ((float*)Out)[(size_t)m * DIM + n] = v;
                else     ((ushort_t*)Out)[(size_t)m * DIM + n] = f2bf(v);
            }
}

// ---------------------------------------------------------------------------
// Last-resort fallback (ws < 16.03 MB): R6 fused gather attention.
// ---------------------------------------------------------------------------
__global__ __launch_bounds__(1024)
void attn_fb_kernel(const int* __restrict__ flag, const ushort_t* __restrict__ Q,
                    const void* __restrict__ emb, const void* __restrict__ Wv,
                    const void* __restrict__ bv, void* __restrict__ Out)
{
    __shared__ ushort_t Qlds[32][LDA];
    __shared__ ushort_t Plds[2][32][LDP];
    __shared__ float    Lpart[16][32];

    const bool f32 = (*flag == 0);
    const int tid  = threadIdx.x;
    const int wave = tid >> 6;
    const int lane = tid & 63;
    const int quad = lane >> 4;
    const int col  = lane & 15;
    const int q0   = blockIdx.x * 32;

    #pragma unroll
    for (int i = 0; i < 2; ++i) {
        int chunk = i * 1024 + tid;
        int row = chunk >> 6;
        int k8  = (chunk & 63) * 8;
        *(bf16x8*)&Qlds[row][k8] = *(const bf16x8*)&Q[(size_t)(q0 + row) * 512 + k8];
    }
    __syncthreads();

    f32x4 accO[2][2];
    #pragma unroll
    for (int r = 0; r < 2; ++r)
        #pragma unroll
        for (int c = 0; c < 2; ++c) accO[r][c] = (f32x4){0.f, 0.f, 0.f, 0.f};

    float lsum[2][4];
    #pragma unroll
    for (int r = 0; r < 2; ++r)
        #pragma unroll
        for (int g = 0; g < 4; ++g) lsum[r][g] = 0.f;

    const float sc = 0.04419417382415922f * 1.4426950408889634f;
    const int wOcol = wave * 32;

    for (int it = 0; it < 32; ++it) {
        const int j0  = it * 256;
        const int buf = it & 1;

        bf16x8 kb[16];
        const size_t keyrow = (size_t)(j0 + wave * 16 + col) * 512;
        #pragma unroll
        for (int kk = 0; kk < 16; ++kk)
            kb[kk] = *(const bf16x8*)&Q[keyrow + kk * 32 + quad * 8];

        f32x4 accS[2];
        accS[0] = (f32x4){0.f, 0.f, 0.f, 0.f};
        accS[1] = (f32x4){0.f, 0.f, 0.f, 0.f};
        #pragma unroll
        for (int kk = 0; kk < 16; ++kk) {
            bf16x8 a0 = *(const bf16x8*)&Qlds[col][kk * 32 + quad * 8];
            bf16x8 a1 = *(const bf16x8*)&Qlds[16 + col][kk * 32 + quad * 8];
            accS[0] = mfma16(a0, kb[kk], accS[0]);
            accS[1] = mfma16(a1, kb[kk], accS[1]);
        }

        bf16x8 vb[16];
        #pragma unroll
        for (int kk = 0; kk < 8; ++kk)
            #pragma unroll
            for (int c = 0; c < 2; ++c) {
                size_t base = (size_t)(j0 + kk * 32 + quad * 8) * 512 + (wOcol + c * 16 + col);
                bf16x8 b;
                if (f32) {
                    const float* bp = (const float*)emb + base;
                    #pragma unroll
                    for (int j = 0; j < 8; ++j) b[j] = f2bfh(bp[(size_t)j * 512]);
                } else {
                    const __bf16* bp = (const __bf16*)emb + base;
                    #pragma unroll
                    for (int j = 0; j < 8; ++j) b[j] = bp[(size_t)j * 512];
                }
                vb[kk * 2 + c] = b;
            }

        #pragma unroll
        for (int r = 0; r < 2; ++r)
            #pragma unroll
            for (int g = 0; g < 4; ++g) {
                float p = exp2f(fminf(accS[r][g] * sc, 126.0f));
                lsum[r][g] += p;
                Plds[buf][r * 16 + quad * 4 + g][wave * 16 + col] = f2bf(p);
            }

        __syncthreads();

        #pragma unroll
        for (int kk = 0; kk < 8; ++kk) {
            bf16x8 a0 = *(const bf16x8*)&Plds[buf][col][kk * 32 + quad * 8];
            bf16x8 a1 = *(const bf16x8*)&Plds[buf][16 + col][kk * 32 + quad * 8];
            #pragma unroll
            for (int c = 0; c < 2; ++c) {
                accO[0][c] = mfma16(a0, vb[kk * 2 + c], accO[0][c]);
                accO[1][c] = mfma16(a1, vb[kk * 2 + c], accO[1][c]);
            }
        }
    }

    #pragma unroll
    for (int r = 0; r < 2; ++r)
        #pragma unroll
        for (int g = 0; g < 4; ++g) {
            float s = lsum[r][g];
            s += __shfl_xor(s, 1);
            s += __shfl_xor(s, 2);
            s += __shfl_xor(s, 4);
            s += __shfl_xor(s, 8);
            lsum[r][g] = s;
        }
    if (col == 0) {
        #pragma unroll
        for (int r = 0; r < 2; ++r)
            #pragma unroll
            for (int g = 0; g < 4; ++g)
                Lpart[wave][r * 16 + quad * 4 + g] = lsum[r][g];
    }
    __syncthreads();

    #pragma unroll
    for (int r = 0; r < 2; ++r) {
        float rinv[4];
        #pragma unroll
        for (int g = 0; g < 4; ++g) {
            float t = 0.f;
            #pragma unroll
            for (int w = 0; w < 16; ++w) t += Lpart[w][r * 16 + quad * 4 + g];
            rinv[g] = 1.0f / t;
        }
        #pragma unroll
        for (int c = 0; c < 2; ++c)
            #pragma unroll
            for (int g = 0; g < 4; ++g)
                Qlds[r * 16 + quad * 4 + g][wOcol + c * 16 + col] = f2bf(accO[r][c][g] * rinv[g]);
    }
    __syncthreads();

    f32x4 acc2[2][2];
    #pragma unroll
    for (int r = 0; r < 2; ++r)
        #pragma unroll
        for (int c = 0; c < 2; ++c) acc2[r][c] = (f32x4){0.f, 0.f, 0.f, 0.f};

    #pragma unroll
    for (int kk = 0; kk < 16; ++kk) {
        bf16x8 a0 = *(const bf16x8*)&Qlds[col][kk * 32 + quad * 8];
        bf16x8 a1 = *(const bf16x8*)&Qlds[16 + col][kk * 32 + quad * 8];
        #pragma unroll
        for (int c = 0; c < 2; ++c) {
            bf16x8 b = load8(Wv, (size_t)(wOcol + c * 16 + col) * 512 + kk * 32 + quad * 8, f32);
            acc2[0][c] = mfma16(a0, b, acc2[0][c]);
            acc2[1][c] = mfma16(a1, b, acc2[1][c]);
        }
    }

    #pragma unroll
    for (int r = 0; r < 2; ++r)
        #pragma unroll
        for (int c = 0; c < 2; ++c)
            #pragma unroll
            for (int g = 0; g < 4; ++g) {
                int m = q0 + r * 16 + quad * 4 + g;
                int n = wOcol + c * 16 + col;
                float v = acc2[r][c][g] + loadS(bv, n, f32);
                if (f32) ((float*)Out)[(size_t)m * DIM + n] = v;
                else     ((ushort_t*)Out)[(size_t)m * DIM + n] = f2bf(v);
            }
}

extern "C" void kernel_launch(void* const* d_in, const int* in_sizes, int n_in,
                              void* d_out, int out_size, void* d_ws, size_t ws_size,
                              hipStream_t stream)
{
    const void* emb = d_in[0];
    const void* Wqk = d_in[1];
    const void* bqk = d_in[2];
    const void* Wv  = d_in[3];
    const void* bv  = d_in[4];

    char* W = (char*)d_ws;
    int*      flag  = (int*)W;
    float*    lsumG = (float*)(W + 64);                      // 32 KB
    ushort_t* embT  = (ushort_t*)(W + 64 + 32768);           // 8 MB
    ushort_t* Qws   = embT + (size_t)DIM * NTOK;             // 8 MB (reused as T)

    const size_t OB4  = (size_t)NTOK * DIM * 4;              // 16 MB fp32
    const size_t base = 64 + 32768 + 2 * (size_t)NTOK * DIM * 2;  // 16.03 MB
    float* P0 = (float*)(W + base);
    float* P1 = P0 + (size_t)NTOK * DIM;
    float* P2 = P1 + (size_t)NTOK * DIM;

    const size_t needA = base + 3 * OB4;                     // ~64.05 MB
    const size_t needB = base;                               // proven available

    detect_kernel<<<dim3(1), dim3(64), 0, stream>>>((const ushort_t*)emb, flag);

    if (ws_size >= needA) {
        transpose_kernel<<<dim3(128, 8), dim3(256), 0, stream>>>(flag, emb, embT,
                                                                 (float4*)lsumG);
        projq_kernel<<<dim3(NTOK / 32), dim3(512), 0, stream>>>(flag, emb, Wqk, bqk, Qws);
        attn128_kernel<<<dim3(256), dim3(1024), 0, stream>>>(Qws, embT,
                                                             P0, P1, P2, (float*)d_out, lsumG);
        reduce_kernel<<<dim3(2048), dim3(256), 0, stream>>>(4, 1, P0, P1, P2, d_out,
                                                            lsumG, Qws);
        projv_kernel<<<dim3(NTOK / 32), dim3(512), 0, stream>>>(flag, Qws, Wv, bv, d_out);
    } else if (ws_size >= needB) {
        transpose_kernel<<<dim3(128, 8), dim3(256), 0, stream>>>(flag, emb, embT,
                                                                 (float4*)lsumG);
        projq_kernel<<<dim3(NTOK / 32), dim3(512), 0, stream>>>(flag, emb, Wqk, bqk, Qws);
        attn64_kernel<<<dim3(256), dim3(1024), 0, stream>>>(Qws, embT,
                                                            (ushort_t*)d_out, lsumG);
        reduce_kernel<<<dim3(2048), dim3(256), 0, stream>>>(2, 0, d_out,
            (const void*)((ushort_t*)d_out + (size_t)NTOK * DIM), nullptr, nullptr,
            lsumG, Qws);
        projv_kernel<<<dim3(NTOK / 32), dim3(512), 0, stream>>>(flag, Qws, Wv, bv, d_out);
    } else {
        ushort_t* Qsm = (ushort_t*)(W + 64);
        projq_kernel<<<dim3(NTOK / 32), dim3(512), 0, stream>>>(flag, emb, Wqk, bqk, Qsm);
        attn_fb_kernel<<<dim3(NTOK / 32), dim3(1024), 0, stream>>>(flag, Qsm, emb, Wv, bv, d_out);
    }
}

// Round 11
// 441.119 us; speedup vs baseline: 1.7995x; 1.3539x over previous
//
#include <hip/hip_runtime.h>
#include <hip/hip_bf16.h>

// N=8192, D=512.  Q = emb@Wqk^T+bqk (K==Q); out = softmax(QK^T/sqrt(512)) @ V.
// Softmax rows sum to 1 => out = (softmax(S)@emb) @ Wv^T + bv (V never built).
// Device dtype runtime-detected (fp32 observed). Internal: bf16 MFMA, fp32 acc.
// R10 post-mortem: Tq=128/16-wave needs accO=64/wave -> spill (no register
// room); best proven kernel is R8's attn64 (382us) taxed ~80-100us by
// device-atomic merges. R11: attn64 with NO atomics — plain fp32 partial
// stores to 2 disjoint ws buffers (full coverage, poison-proof) + per-split
// lsum arrays (cross-wave LDS reduce); finalize fuses reduce+normalize+Wv
// projection. 5 launches. ws need 48.1 MB (ws>=64MB proven by R10 Path A).

#define NTOK 8192
#define DIM  512

typedef unsigned short ushort_t;
typedef __attribute__((ext_vector_type(8))) __bf16 bf16x8;
typedef __attribute__((ext_vector_type(4))) float f32x4;

__device__ __forceinline__ float bf2f(ushort_t u) {
    union { unsigned int i; float f; } v; v.i = ((unsigned int)u) << 16; return v.f;
}
__device__ __forceinline__ ushort_t f2bf(float f) {
    union { float f; unsigned int i; } v; v.f = f;
    unsigned int b = v.i;
    return (ushort_t)((b + 0x7FFFu + ((b >> 16) & 1u)) >> 16);   // RNE
}
__device__ __forceinline__ __bf16 f2bfh(float f) {
    union { ushort_t u; __bf16 h; } c; c.u = f2bf(f); return c.h;
}
__device__ __forceinline__ f32x4 mfma16(bf16x8 a, bf16x8 b, f32x4 c) {
    return __builtin_amdgcn_mfma_f32_16x16x32_bf16(a, b, c, 0, 0, 0);
}
__device__ __forceinline__ bf16x8 load8(const void* p, size_t idx, bool f32) {
    if (f32) {
        const float* f = (const float*)p + idx;
        bf16x8 r;
        #pragma unroll
        for (int j = 0; j < 8; ++j) r[j] = f2bfh(f[j]);
        return r;
    }
    return *(const bf16x8*)((const ushort_t*)p + idx);
}
__device__ __forceinline__ float loadS(const void* p, size_t idx, bool f32) {
    return f32 ? ((const float*)p)[idx] : bf2f(((const ushort_t*)p)[idx]);
}

#define LDA 520   // 260 dw, %32=4: uniform 2 dw/bank for b128 row reads
#define LDP 264

// ---------------------------------------------------------------------------
// Dtype probe: flag=1 => bf16 data, flag=0 => fp32.
// ---------------------------------------------------------------------------
__global__ void detect_kernel(const ushort_t* __restrict__ emb, int* __restrict__ flag)
{
    int lane = threadIdx.x;
    int cnt = 0;
    #pragma unroll
    for (int i = 0; i < 8; ++i) {
        ushort_t u = emb[(size_t)(lane * 8 + i) * 2];
        int a = u & 0x7FFF;
        int e = (u >> 7) & 0xFF;
        if (a == 0 || (e >= 111 && e <= 143)) cnt++;
    }
    cnt += __shfl_xor(cnt, 1);  cnt += __shfl_xor(cnt, 2);  cnt += __shfl_xor(cnt, 4);
    cnt += __shfl_xor(cnt, 8);  cnt += __shfl_xor(cnt, 16); cnt += __shfl_xor(cnt, 32);
    if (lane == 0) *flag = (cnt >= 460) ? 1 : 0;
}

// ---------------------------------------------------------------------------
// embT[512][8192] (bf16) = emb^T.
// ---------------------------------------------------------------------------
__global__ __launch_bounds__(256)
void transpose_kernel(const int* __restrict__ flag, const void* __restrict__ emb,
                      ushort_t* __restrict__ embT)
{
    __shared__ float tile[64][65];
    const bool f32 = (*flag == 0);
    const int t  = threadIdx.x;
    const int j0 = blockIdx.x * 64;
    const int d0 = blockIdx.y * 64;
    {
        int r = t >> 2, cs = (t & 3) * 16;
        if (f32) {
            const float* src = (const float*)emb + (size_t)(j0 + r) * DIM + d0 + cs;
            #pragma unroll
            for (int i = 0; i < 16; i += 4) {
                float4 v = *(const float4*)(src + i);
                tile[r][cs + i]     = v.x;
                tile[r][cs + i + 1] = v.y;
                tile[r][cs + i + 2] = v.z;
                tile[r][cs + i + 3] = v.w;
            }
        } else {
            const ushort_t* src = (const ushort_t*)emb + (size_t)(j0 + r) * DIM + d0 + cs;
            #pragma unroll
            for (int i = 0; i < 16; ++i) tile[r][cs + i] = bf2f(src[i]);
        }
    }
    __syncthreads();
    {
        int d = t >> 2, js = (t & 3) * 16;
        ushort_t buf[16];
        #pragma unroll
        for (int i = 0; i < 16; ++i) buf[i] = f2bf(tile[js + i][d]);
        ushort_t* dst = embT + (size_t)(d0 + d) * NTOK + j0 + js;
        *(uint4*)dst       = *(uint4*)&buf[0];
        *(uint4*)(dst + 8) = *(uint4*)&buf[8];
    }
}

// ---------------------------------------------------------------------------
// Q[8192][512](bf16, ws) = emb @ Wqk^T + bqk.  512 thr, 8 waves.
// ---------------------------------------------------------------------------
__global__ __launch_bounds__(512)
void projq_kernel(const int* __restrict__ flag, const void* __restrict__ emb,
                  const void* __restrict__ W, const void* __restrict__ bias,
                  ushort_t* __restrict__ C)
{
    __shared__ ushort_t Alds[32][LDA];
    const bool f32 = (*flag == 0);
    const int tid  = threadIdx.x;
    const int wave = tid >> 6;
    const int lane = tid & 63;
    const int quad = lane >> 4;
    const int col  = lane & 15;
    const int mblk = blockIdx.x * 32;

    #pragma unroll
    for (int i = 0; i < 4; ++i) {
        int chunk = i * 512 + tid;
        int row = chunk >> 6;
        int k8  = (chunk & 63) * 8;
        *(bf16x8*)&Alds[row][k8] = load8(emb, (size_t)(mblk + row) * 512 + k8, f32);
    }
    __syncthreads();

    f32x4 acc[2][4];
    #pragma unroll
    for (int r = 0; r < 2; ++r)
        #pragma unroll
        for (int c = 0; c < 4; ++c) acc[r][c] = (f32x4){0.f, 0.f, 0.f, 0.f};

    const int wcol = wave * 64;
    #pragma unroll
    for (int kk = 0; kk < 16; ++kk) {
        bf16x8 a0 = *(const bf16x8*)&Alds[col][kk * 32 + quad * 8];
        bf16x8 a1 = *(const bf16x8*)&Alds[16 + col][kk * 32 + quad * 8];
        #pragma unroll
        for (int c = 0; c < 4; ++c) {
            bf16x8 b = load8(W, (size_t)(wcol + c * 16 + col) * 512 + kk * 32 + quad * 8, f32);
            acc[0][c] = mfma16(a0, b, acc[0][c]);
            acc[1][c] = mfma16(a1, b, acc[1][c]);
        }
    }

    #pragma unroll
    for (int r = 0; r < 2; ++r)
        #pragma unroll
        for (int c = 0; c < 4; ++c)
            #pragma unroll
            for (int g = 0; g < 4; ++g) {
                int m = mblk + r * 16 + quad * 4 + g;
                int n = wcol + c * 16 + col;
                C[(size_t)m * DIM + n] = f2bf(acc[r][c][g] + loadS(bias, n, f32));
            }
}

// ---------------------------------------------------------------------------
// Attention partials (R8 shape, atomic-free): 256 blocks = 128 q-tiles (Tq=64)
// x 2 key-halves, 1024 thr = 16 waves, KT=256 (16 iters).
// Wave w: S for keys [16w,16w+16) x 64 rows; owns D cols [32w,32w+32) in PV.
// fp32 partial O stored plain into P[ks] (disjoint, full coverage); per-split
// row sums via cross-wave LDS reduce into lsumA[ks][row] (no atomics at all).
// ---------------------------------------------------------------------------
__global__ __launch_bounds__(1024)
void attn64_kernel(const ushort_t* __restrict__ Q, const ushort_t* __restrict__ embT,
                   float* __restrict__ P0, float* __restrict__ P1,
                   float* __restrict__ lsumA)
{
    __shared__ ushort_t Qlds[64][LDA];    // 66,560 B
    __shared__ ushort_t Plds[64][LDP];    // 33,792 B
    __shared__ float    Lp[16][64];       //  4,096 B

    const int tid  = threadIdx.x;
    const int wave = tid >> 6;
    const int lane = tid & 63;
    const int quad = lane >> 4;
    const int col  = lane & 15;
    const int qt   = blockIdx.x & 127;
    const int ks   = blockIdx.x >> 7;
    const int q0   = qt * 64;
    const int kbase = ks * 4096;
    float* Ps = ks ? P1 : P0;

    #pragma unroll
    for (int i = 0; i < 4; ++i) {
        int chunk = i * 1024 + tid;
        int row = chunk >> 6;
        int k8  = (chunk & 63) * 8;
        *(bf16x8*)&Qlds[row][k8] = *(const bf16x8*)&Q[(size_t)(q0 + row) * 512 + k8];
    }
    __syncthreads();

    f32x4 accO[4][2];
    #pragma unroll
    for (int r = 0; r < 4; ++r)
        #pragma unroll
        for (int c = 0; c < 2; ++c) accO[r][c] = (f32x4){0.f, 0.f, 0.f, 0.f};

    float lsum[4][4];
    #pragma unroll
    for (int r = 0; r < 4; ++r)
        #pragma unroll
        for (int g = 0; g < 4; ++g) lsum[r][g] = 0.f;

    const float sc = 0.04419417382415922f * 1.4426950408889634f;  // 1/sqrt(512)*log2e
    const int wd = wave * 32;

    for (int it = 0; it < 16; ++it) {
        const int j0 = kbase + it * 256;

        bf16x8 kb[16];
        const size_t keyrow = (size_t)(j0 + wave * 16 + col) * 512;
        #pragma unroll
        for (int kk = 0; kk < 16; ++kk)
            kb[kk] = *(const bf16x8*)&Q[keyrow + kk * 32 + quad * 8];

        f32x4 accS[4];
        #pragma unroll
        for (int r = 0; r < 4; ++r) accS[r] = (f32x4){0.f, 0.f, 0.f, 0.f};
        #pragma unroll
        for (int kk = 0; kk < 16; ++kk) {
            #pragma unroll
            for (int r = 0; r < 4; ++r) {
                bf16x8 a = *(const bf16x8*)&Qlds[r * 16 + col][kk * 32 + quad * 8];
                accS[r] = mfma16(a, kb[kk], accS[r]);
            }
        }

        bf16x8 vb[16];
        #pragma unroll
        for (int kk = 0; kk < 8; ++kk)
            #pragma unroll
            for (int c = 0; c < 2; ++c)
                vb[kk * 2 + c] = *(const bf16x8*)&embT[
                    (size_t)(wd + c * 16 + col) * NTOK + j0 + kk * 32 + quad * 8];

        __syncthreads();   // previous iter's PV reads of Plds done

        #pragma unroll
        for (int r = 0; r < 4; ++r)
            #pragma unroll
            for (int g = 0; g < 4; ++g) {
                float p = exp2f(fminf(accS[r][g] * sc, 126.0f));
                lsum[r][g] += p;
                Plds[r * 16 + quad * 4 + g][wave * 16 + col] = f2bf(p);
            }

        __syncthreads();   // P visible to all waves

        #pragma unroll
        for (int kk = 0; kk < 8; ++kk) {
            #pragma unroll
            for (int r = 0; r < 4; ++r) {
                bf16x8 a = *(const bf16x8*)&Plds[r * 16 + col][kk * 32 + quad * 8];
                #pragma unroll
                for (int c = 0; c < 2; ++c)
                    accO[r][c] = mfma16(a, vb[kk * 2 + c], accO[r][c]);
            }
        }
    }

    // ---- row sums: lane-reduce (16 key-lanes) then cross-wave LDS reduce ----
    #pragma unroll
    for (int r = 0; r < 4; ++r)
        #pragma unroll
        for (int g = 0; g < 4; ++g) {
            float s = lsum[r][g];
            s += __shfl_xor(s, 1);
            s += __shfl_xor(s, 2);
            s += __shfl_xor(s, 4);
            s += __shfl_xor(s, 8);
            if (col == 0)
                Lp[wave][r * 16 + quad * 4 + g] = s;
        }
    __syncthreads();
    if (tid < 64) {
        float t = 0.f;
        #pragma unroll
        for (int w = 0; w < 16; ++w) t += Lp[w][tid];
        lsumA[(size_t)ks * NTOK + q0 + tid] = t;
    }

    // ---- plain fp32 partial store (disjoint, full 64x512 coverage) ----
    #pragma unroll
    for (int r = 0; r < 4; ++r)
        #pragma unroll
        for (int c = 0; c < 2; ++c)
            #pragma unroll
            for (int g = 0; g < 4; ++g)
                Ps[(size_t)(q0 + r * 16 + quad * 4 + g) * DIM + wd + c * 16 + col]
                    = accO[r][c][g];
}

// ---------------------------------------------------------------------------
// Finalize: T = (P0+P1)/(l0+l1) (bf16, in LDS), out = T @ Wv^T + bv.
// 256 blocks x 512 thr, 32 rows/block.
// ---------------------------------------------------------------------------
__global__ __launch_bounds__(512)
void finalize_kernel(const int* __restrict__ flag,
                     const float* __restrict__ P0, const float* __restrict__ P1,
                     const float* __restrict__ lsumA,
                     const void* __restrict__ Wv, const void* __restrict__ bv,
                     void* __restrict__ Out)
{
    __shared__ ushort_t Alds[32][LDA];
    const bool f32 = (*flag == 0);
    const int tid  = threadIdx.x;
    const int wave = tid >> 6;
    const int lane = tid & 63;
    const int quad = lane >> 4;
    const int col  = lane & 15;
    const int mblk = blockIdx.x * 32;

    #pragma unroll
    for (int i = 0; i < 4; ++i) {
        int chunk = i * 512 + tid;
        int row = chunk >> 6;
        int k8  = (chunk & 63) * 8;
        int m   = mblk + row;
        float rv = 1.0f / (lsumA[m] + lsumA[NTOK + m]);
        const float* s0 = P0 + (size_t)m * 512 + k8;
        const float* s1 = P1 + (size_t)m * 512 + k8;
        bf16x8 t;
        #pragma unroll
        for (int j = 0; j < 8; ++j) t[j] = f2bfh((s0[j] + s1[j]) * rv);
        *(bf16x8*)&Alds[row][k8] = t;
    }
    __syncthreads();

    f32x4 acc[2][4];
    #pragma unroll
    for (int r = 0; r < 2; ++r)
        #pragma unroll
        for (int c = 0; c < 4; ++c) acc[r][c] = (f32x4){0.f, 0.f, 0.f, 0.f};

    const int wcol = wave * 64;
    #pragma unroll
    for (int kk = 0; kk < 16; ++kk) {
        bf16x8 a0 = *(const bf16x8*)&Alds[col][kk * 32 + quad * 8];
        bf16x8 a1 = *(const bf16x8*)&Alds[16 + col][kk * 32 + quad * 8];
        #pragma unroll
        for (int c = 0; c < 4; ++c) {
            bf16x8 b = load8(Wv, (size_t)(wcol + c * 16 + col) * 512 + kk * 32 + quad * 8, f32);
            acc[0][c] = mfma16(a0, b, acc[0][c]);
            acc[1][c] = mfma16(a1, b, acc[1][c]);
        }
    }

    #pragma unroll
    for (int r = 0; r < 2; ++r)
        #pragma unroll
        for (int c = 0; c < 4; ++c)
            #pragma unroll
            for (int g = 0; g < 4; ++g) {
                int m = mblk + r * 16 + quad * 4 + g;
                int n = wcol + c * 16 + col;
                float v = acc[r][c][g] + loadS(bv, n, f32);
                if (f32) ((float*)Out)[(size_t)m * DIM + n] = v;
                else     ((ushort_t*)Out)[(size_t)m * DIM + n] = f2bf(v);
            }
}

// ---------------------------------------------------------------------------
// Mid-ws fallback: R6-proven fused attention + V-projection (needs 16.03 MB).
// ---------------------------------------------------------------------------
template <int VT>
__global__ __launch_bounds__(1024)
void attn_fused_kernel(const int* __restrict__ flag, const ushort_t* __restrict__ Q,
                       const void* __restrict__ embOrT, const void* __restrict__ Wv,
                       const void* __restrict__ bv, void* __restrict__ Out)
{
    __shared__ ushort_t Qlds[32][LDA];
    __shared__ ushort_t Plds[2][32][LDP];
    __shared__ float    Lpart[16][32];

    const bool f32 = (*flag == 0);
    const int tid  = threadIdx.x;
    const int wave = tid >> 6;
    const int lane = tid & 63;
    const int quad = lane >> 4;
    const int col  = lane & 15;
    const int q0   = blockIdx.x * 32;

    #pragma unroll
    for (int i = 0; i < 2; ++i) {
        int chunk = i * 1024 + tid;
        int row = chunk >> 6;
        int k8  = (chunk & 63) * 8;
        *(bf16x8*)&Qlds[row][k8] = *(const bf16x8*)&Q[(size_t)(q0 + row) * 512 + k8];
    }
    __syncthreads();

    f32x4 accO[2][2];
    #pragma unroll
    for (int r = 0; r < 2; ++r)
        #pragma unroll
        for (int c = 0; c < 2; ++c) accO[r][c] = (f32x4){0.f, 0.f, 0.f, 0.f};

    float lsum[2][4];
    #pragma unroll
    for (int r = 0; r < 2; ++r)
        #pragma unroll
        for (int g = 0; g < 4; ++g) lsum[r][g] = 0.f;

    const float sc = 0.04419417382415922f * 1.4426950408889634f;
    const int wOcol = wave * 32;

    for (int it = 0; it < 32; ++it) {
        const int j0  = it * 256;
        const int buf = it & 1;

        bf16x8 kb[16];
        const size_t keyrow = (size_t)(j0 + wave * 16 + col) * 512;
        #pragma unroll
        for (int kk = 0; kk < 16; ++kk)
            kb[kk] = *(const bf16x8*)&Q[keyrow + kk * 32 + quad * 8];

        f32x4 accS[2];
        accS[0] = (f32x4){0.f, 0.f, 0.f, 0.f};
        accS[1] = (f32x4){0.f, 0.f, 0.f, 0.f};
        #pragma unroll
        for (int kk = 0; kk < 16; ++kk) {
            bf16x8 a0 = *(const bf16x8*)&Qlds[col][kk * 32 + quad * 8];
            bf16x8 a1 = *(const bf16x8*)&Qlds[16 + col][kk * 32 + quad * 8];
            accS[0] = mfma16(a0, kb[kk], accS[0]);
            accS[1] = mfma16(a1, kb[kk], accS[1]);
        }

        bf16x8 vb[16];
        #pragma unroll
        for (int kk = 0; kk < 8; ++kk)
            #pragma unroll
            for (int c = 0; c < 2; ++c) {
                if (VT) {
                    vb[kk * 2 + c] = *(const bf16x8*)((const ushort_t*)embOrT
                        + (size_t)(wOcol + c * 16 + col) * NTOK + j0 + kk * 32 + quad * 8);
                } else {
                    size_t base = (size_t)(j0 + kk * 32 + quad * 8) * 512 + (wOcol + c * 16 + col);
                    bf16x8 b;
                    if (f32) {
                        const float* bp = (const float*)embOrT + base;
                        #pragma unroll
                        for (int j = 0; j < 8; ++j) b[j] = f2bfh(bp[(size_t)j * 512]);
                    } else {
                        const __bf16* bp = (const __bf16*)embOrT + base;
                        #pragma unroll
                        for (int j = 0; j < 8; ++j) b[j] = bp[(size_t)j * 512];
                    }
                    vb[kk * 2 + c] = b;
                }
            }

        #pragma unroll
        for (int r = 0; r < 2; ++r)
            #pragma unroll
            for (int g = 0; g < 4; ++g) {
                float p = exp2f(fminf(accS[r][g] * sc, 126.0f));
                lsum[r][g] += p;
                Plds[buf][r * 16 + quad * 4 + g][wave * 16 + col] = f2bf(p);
            }

        __syncthreads();

        #pragma unroll
        for (int kk = 0; kk < 8; ++kk) {
            bf16x8 a0 = *(const bf16x8*)&Plds[buf][col][kk * 32 + quad * 8];
            bf16x8 a1 = *(const bf16x8*)&Plds[buf][16 + col][kk * 32 + quad * 8];
            #pragma unroll
            for (int c = 0; c < 2; ++c) {
                accO[0][c] = mfma16(a0, vb[kk * 2 + c], accO[0][c]);
                accO[1][c] = mfma16(a1, vb[kk * 2 + c], accO[1][c]);
            }
        }
    }

    #pragma unroll
    for (int r = 0; r < 2; ++r)
        #pragma unroll
        for (int g = 0; g < 4; ++g) {
            float s = lsum[r][g];
            s += __shfl_xor(s, 1);
            s += __shfl_xor(s, 2);
            s += __shfl_xor(s, 4);
            s += __shfl_xor(s, 8);
            lsum[r][g] = s;
        }
    if (col == 0) {
        #pragma unroll
        for (int r = 0; r < 2; ++r)
            #pragma unroll
            for (int g = 0; g < 4; ++g)
                Lpart[wave][r * 16 + quad * 4 + g] = lsum[r][g];
    }
    __syncthreads();

    #pragma unroll
    for (int r = 0; r < 2; ++r) {
        float rinv[4];
        #pragma unroll
        for (int g = 0; g < 4; ++g) {
            float t = 0.f;
            #pragma unroll
            for (int w = 0; w < 16; ++w) t += Lpart[w][r * 16 + quad * 4 + g];
            rinv[g] = 1.0f / t;
        }
        #pragma unroll
        for (int c = 0; c < 2; ++c)
            #pragma unroll
            for (int g = 0; g < 4; ++g)
                Qlds[r * 16 + quad * 4 + g][wOcol + c * 16 + col] = f2bf(accO[r][c][g] * rinv[g]);
    }
    __syncthreads();

    f32x4 acc2[2][2];
    #pragma unroll
    for (int r = 0; r < 2; ++r)
        #pragma unroll
        for (int c = 0; c < 2; ++c) acc2[r][c] = (f32x4){0.f, 0.f, 0.f, 0.f};

    #pragma unroll
    for (int kk = 0; kk < 16; ++kk) {
        bf16x8 a0 = *(const bf16x8*)&Qlds[col][kk * 32 + quad * 8];
        bf16x8 a1 = *(const bf16x8*)&Qlds[16 + col][kk * 32 + quad * 8];
        #pragma unroll
        for (int c = 0; c < 2; ++c) {
            bf16x8 b = load8(Wv, (size_t)(wOcol + c * 16 + col) * 512 + kk * 32 + quad * 8, f32);
            acc2[0][c] = mfma16(a0, b, acc2[0][c]);
            acc2[1][c] = mfma16(a1, b, acc2[1][c]);
        }
    }

    #pragma unroll
    for (int r = 0; r < 2; ++r)
        #pragma unroll
        for (int c = 0; c < 2; ++c)
            #pragma unroll
            for (int g = 0; g < 4; ++g) {
                int m = q0 + r * 16 + quad * 4 + g;
                int n = wOcol + c * 16 + col;
                float v = acc2[r][c][g] + loadS(bv, n, f32);
                if (f32) ((float*)Out)[(size_t)m * DIM + n] = v;
                else     ((ushort_t*)Out)[(size_t)m * DIM + n] = f2bf(v);
            }
}

extern "C" void kernel_launch(void* const* d_in, const int* in_sizes, int n_in,
                              void* d_out, int out_size, void* d_ws, size_t ws_size,
                              hipStream_t stream)
{
    const void* emb = d_in[0];
    const void* Wqk = d_in[1];
    const void* bqk = d_in[2];
    const void* Wv  = d_in[3];
    const void* bv  = d_in[4];

    char* W = (char*)d_ws;
    int*      flag  = (int*)W;
    float*    lsumA = (float*)(W + 64);                        // 2x8192 fp32 = 64 KB
    ushort_t* embT  = (ushort_t*)(W + 64 + 65536);             // 8 MB
    ushort_t* Qws   = embT + (size_t)DIM * NTOK;               // 8 MB
    float*    P0    = (float*)((char*)(Qws + (size_t)DIM * NTOK)); // 16 MB
    float*    P1    = P0 + (size_t)NTOK * DIM;                 // 16 MB

    const size_t needA = 64 + 65536 + 2 * (size_t)NTOK * DIM * 2
                       + 2 * (size_t)NTOK * DIM * 4;           // ~48.1 MB (ws>=64MB proven)
    const size_t needB = 64 + 2 * (size_t)NTOK * DIM * 2;      // 16.03 MB

    detect_kernel<<<dim3(1), dim3(64), 0, stream>>>((const ushort_t*)emb, flag);

    if (ws_size >= needA) {
        transpose_kernel<<<dim3(128, 8), dim3(256), 0, stream>>>(flag, emb, embT);
        projq_kernel<<<dim3(NTOK / 32), dim3(512), 0, stream>>>(flag, emb, Wqk, bqk, Qws);
        attn64_kernel<<<dim3(256), dim3(1024), 0, stream>>>(Qws, embT, P0, P1, lsumA);
        finalize_kernel<<<dim3(NTOK / 32), dim3(512), 0, stream>>>(flag, P0, P1, lsumA,
                                                                   Wv, bv, d_out);
    } else if (ws_size >= needB) {
        ushort_t* embT2 = (ushort_t*)(W + 64);
        ushort_t* Qws2  = embT2 + (size_t)DIM * NTOK;
        transpose_kernel<<<dim3(128, 8), dim3(256), 0, stream>>>(flag, emb, embT2);
        projq_kernel<<<dim3(NTOK / 32), dim3(512), 0, stream>>>(flag, emb, Wqk, bqk, Qws2);
        attn_fused_kernel<1><<<dim3(NTOK / 32), dim3(1024), 0, stream>>>(
            flag, Qws2, embT2, Wv, bv, d_out);
    } else {
        ushort_t* Qsm = (ushort_t*)(W + 64);
        projq_kernel<<<dim3(NTOK / 32), dim3(512), 0, stream>>>(flag, emb, Wqk, bqk, Qsm);
        attn_fused_kernel<0><<<dim3(NTOK / 32), dim3(1024), 0, stream>>>(
            flag, Qsm, emb, Wv, bv, d_out);
    }
}